// Round 2
// baseline (170.702 us; speedup 1.0000x reference)
//
#include <hip/hip_runtime.h>
#include <math.h>

// Problem constants (fixed by the reference).
#define NITEMS 50000
#define BATCH  512
#define LLEN   50
#define KTOP   20
#define HDIM   32
#define DDIM   32
#define NCH    5
#define NSEG   33             // H+1 piecewise-linear segments
#define NSCAL  200            // scalars per item
#define NCELL  100            // (c,k) cells
#define THRP   33             // padded LDS stride for sorted thresholds
#define NWAVE  8              // waves per block
#define CSLOT  13             // ceil(100/8) cells per 8-lane group

typedef _Float16 h2 __attribute__((ext_vector_type(2)));

static __device__ __forceinline__ float dot2_acc(h2 a, h2 b, float c) {
#if __has_builtin(__builtin_amdgcn_fdot2)
    return __builtin_amdgcn_fdot2(a, b, c, false);
#else
    return fmaf((float)a.x, (float)b.x, fmaf((float)a.y, (float)b.y, c));
#endif
}

// ---------------------------------------------------------------------------
// R13 = R12 (single-kernel fold of setup into a per-block prologue) with the
// GPU-fault paths hardened:
//   * sBp pre-initialized to an in-bounds fallback (if the rank->row scan
//     ever failed to write, R12 read uninitialized LDS -> OOB ctx/out
//     addresses -> memory fault -> container death, matching the round-1
//     "container failed twice" signature).
//   * lstar guarded against an empty ballot (ctzll(0) is UB); need clamped.
//   * b masked into [0, BATCH) -- a wrong b now degrades to an absmax
//     failure instead of a fault.
// Main body is R9/R11 VERBATIM (spill-fragile; see R7/R10 note: do NOT
// restructure the stripe loop without checking WRITE_SIZE for spills).
// ---------------------------------------------------------------------------
__global__ __launch_bounds__(512, 4) void cnn_main(
        const float* __restrict__ ctx,
        const float* __restrict__ W1g, const float* __restrict__ b1g,
        const float* __restrict__ W2g, const float* __restrict__ b2g,
        const float* __restrict__ Wout, const float* __restrict__ bout,
        const int* __restrict__ item_idxs, const int* __restrict__ user_items,
        const int* __restrict__ user_lens,
        float* __restrict__ out) {
    __shared__ unsigned int sAB16[NCH*NSEG*32];  // 21120 B, swizzled fp16
    __shared__ float  sThrS[NCH*THRP];           // sorted thr, stride 33
    __shared__ uint2  sxo[NWAVE][NCELL];         // {x0h|off0<<16, x1h|off1<<16}
    __shared__ uint2  sWt[NCELL*8];              // [cell*8+d4] target wt bits
    __shared__ float  pRed[NWAVE][NCELL];        // per-wave scalar partials

    const int tid  = threadIdx.x;
    const int w    = tid >> 6;              // wave 0..7
    const int lane = tid & 63;
    const int g    = lane >> 3;             // cell sub-group 0..7
    const int d4   = lane & 7;              // covers d = 4*d4 .. 4*d4+3

    // Sorted pairing (ranks r and 511-r co-resident under round-robin).
    const int rank = (blockIdx.x < 256) ? blockIdx.x : (767 - blockIdx.x);

    // ---- prologue temporaries overlaid on later-phase LDS ----------------
    // pRed (3200 B) is first written in the epilogue; sWt first written in
    // the target phase (by wave 0, after it is done reading sHist).
    float* sW1f  = &pRed[0][0];                  // 160 f
    float* sB1f  = sW1f + NCH*HDIM;              // 160 f
    float* sThrT = sB1f + NCH*HDIM;              // 160 f
    int*   sRank = (int*)(sThrT + NCH*HDIM);     // 160 i
    int*   sBp   = sRank + NCH*HDIM;             // 1 i  (2564 B total <= 3200)
    int*   sHist = (int*)&sWt[0];                // 51 i

    // ---- B0..B1: stage W1/b1, zero histogram, init sBp fallback ----------
    for (int i = tid; i < NCH*HDIM; i += 512) { sW1f[i] = W1g[i]; sB1f[i] = b1g[i]; }
    if (tid <= LLEN) sHist[tid] = 0;
    if (tid == 0) *sBp = rank;                   // in-bounds fallback
    __syncthreads();

    // ---- B1..B2: thresholds; length histogram ----------------------------
    for (int i = tid; i < NCH*HDIM; i += 512) {
        float wv = sW1f[i];
        sThrT[i] = (wv != 0.f) ? (-sB1f[i] / wv) : INFINITY;
    }
    atomicAdd(&sHist[user_lens[tid]], 1);        // counts are order-invariant
    __syncthreads();

    // ---- B2..B3: ranks + sorted-threshold scatter; exclusive prefix ------
    for (int i = tid; i < NCH*HDIM; i += 512) {
        int c = i >> 5, h = i & 31;
        float thr = sThrT[i];
        int rnk = 0;
        for (int hh = 0; hh < HDIM; ++hh) {
            float t2 = sThrT[(c<<5) + hh];
            rnk += (t2 < thr || (t2 == thr && hh < h)) ? 1 : 0;
        }
        sRank[i] = rnk;
        sThrS[c*THRP + rnk] = thr;
    }
    if (tid == 0) {
        int accum = 0;
        for (int l = 1; l <= LLEN; ++l) { int cc = sHist[l]; sHist[l] = accum; accum += cc; }
    }
    __syncthreads();

    // ---- B3..B4: AB fp16 table directly into sAB16 (same math as setup) --
    {
        unsigned short* ab = (unsigned short*)sAB16;
        for (int e = tid; e < NCH*NSEG*DDIM; e += 512) {
            int d  = e & 31;
            int cs = e >> 5;
            int c  = cs / NSEG, s = cs - c*NSEG;
            float A = 0.f, Bv = 0.f;
#pragma unroll
            for (int h = 0; h < HDIM; ++h) {
                float wv = sW1f[(c<<5) + h];
                float bb = sB1f[(c<<5) + h];
                int   r  = sRank[(c<<5) + h];
                bool active = (wv > 0.f) ? (r < s) : ((wv < 0.f) ? (r >= s) : (bb > 0.f));
                if (active) {
                    float w2 = W2g[((c<<5) + h)*DDIM + d];
                    A  = fmaf(wv, w2, A);
                    Bv = fmaf(bb, w2, Bv);
                }
            }
            Bv += b2g[(c<<5) + d];
            int dq = d >> 2, dd = d & 3;
            int base = ((c*NSEG + s)*32 + dq*4)*2;          // ushort index
            _Float16 ah = (_Float16)A, bh = (_Float16)Bv;
            ab[base + 4*(dd>>1) + (dd&1)]     = __builtin_bit_cast(unsigned short, ah);
            ab[base + 4*(dd>>1) + 2 + (dd&1)] = __builtin_bit_cast(unsigned short, bh);
        }
    }
    __syncthreads();

    // ---- B4..B5: wave 0 resolves b = row at sorted position `rank` -------
    // Stable counting-sort lookup: bin l* contains rank; the (rank-start)-th
    // row (by ascending index) with len==l* is our row.  Deterministic, so
    // all 512 blocks agree on the same bijection.
    if (w == 0) {
        int l = lane;
        bool inb = (l >= 1 && l <= LLEN) && (sHist[l] <= rank)
                && (l == LLEN || sHist[l+1] > rank);
        unsigned long long mm = __ballot(inb);
        if (mm != 0ull) {
            int lstar = (int)__builtin_ctzll(mm);
            int need = rank - sHist[lstar];
            if (need < 0) need = 0;
            for (int chunk = 0; chunk < BATCH/64; ++chunk) {
                int j = (chunk << 6) + lane;
                unsigned long long mb = __ballot(user_lens[j] == lstar);
                int cnt = __popcll(mb);
                if (need < cnt) {
                    if (((mb >> lane) & 1ull) &&
                        __popcll(mb & ((1ull << lane) - 1ull)) == need)
                        *sBp = j;
                    break;
                }
                need -= cnt;
            }
        }
    }
    __syncthreads();                        // prologue results visible to all

    // ======================================================================
    // From here on: R9/R11 main body, verbatim (b sourced from sBp).
    // ======================================================================
    const int b    = (*sBp) & (BATCH - 1);  // mask: never out of bounds
    const int len  = user_lens[b];          // >= 1
    const float inv_len = 1.f / (float)len;
    const float bo = bout[0];
    const h2 wv0 = {(_Float16)Wout[4*d4],     (_Float16)Wout[4*d4 + 1]};
    const h2 wv1 = {(_Float16)Wout[4*d4 + 2], (_Float16)Wout[4*d4 + 3]};

    // Per-(lane,round) phase-S constants (fixed across items).
    int sc[4], sdst[4];
#pragma unroll
    for (int r = 0; r < 4; ++r) {
        int idx  = lane + 64*r;
        int c    = idx / 40, rr = idx - c*40;
        int cell = c*KTOP + (rr % KTOP);
        sc[r]   = c;
        sdst[r] = cell*8 + (rr / KTOP)*4;   // byte offset in sxo[w]
    }

    const int nstripe = (len > w) ? ((len - w + NWAVE - 1) / NWAVE) : 0;

    unsigned int wtA[CSLOT], wtB[CSLOT];    // target rep * Wout (h2 bits)
    float acc[CSLOT];
#pragma unroll
    for (int i = 0; i < CSLOT; ++i) acc[i] = 0.f;

    char* sxoB = (char*)&sxo[w][0];

    // Prefetch this wave's first stripe item (overlaps wave 0's target).
    float xp[4] = {0.f, 0.f, 0.f, 0.f};
    if (nstripe > 0) {
        const float* row = ctx + (size_t)user_items[b*LLEN + w] * NSCAL;
#pragma unroll
        for (int r = 0; r < 4; ++r) {
            int idx = lane + 64*r;
            if (idx < NSCAL) xp[r] = row[idx];
        }
    }

    // ======== target item: wave 0 only, broadcast via sWt ================
    if (w == 0) {
        float xt[4] = {0.f, 0.f, 0.f, 0.f};
        const float* row = ctx + (size_t)item_idxs[b] * NSCAL;
#pragma unroll
        for (int r = 0; r < 4; ++r) {
            int idx = lane + 64*r;
            if (idx < NSCAL) xt[r] = row[idx];
        }
#pragma unroll
        for (int r = 0; r < 4; ++r) {
            int idx = lane + 64*r;
            if (idx < NSCAL) {
                float xv = xt[r];
                int base = sc[r]*THRP;
                int pos = 0;
                pos += (sThrS[base + pos + 15] < xv) ? 16 : 0;
                pos += (sThrS[base + pos + 7]  < xv) ? 8  : 0;
                pos += (sThrS[base + pos + 3]  < xv) ? 4  : 0;
                pos += (sThrS[base + pos + 1]  < xv) ? 2  : 0;
                pos += (sThrS[base + pos]      < xv) ? 1  : 0;
                unsigned int off = (unsigned int)((sc[r]*NSEG + pos) << 7);
                _Float16 xh = (_Float16)xv;
                unsigned int word = (unsigned int)__builtin_bit_cast(unsigned short, xh)
                                  | (off << 16);
                *(unsigned int*)(sxoB + sdst[r]) = word;
            }
        }
        __builtin_amdgcn_wave_barrier();
#pragma unroll
        for (int i = 0; i < CSLOT; ++i) {
            int cell = g + 8*i;
            if (cell < NCELL) {
                uint2 xo = sxo[0][cell];
                const uint4* p0 = (const uint4*)((const char*)sAB16 + (xo.x >> 16) + (d4 << 4));
                const uint4* p1 = (const uint4*)((const char*)sAB16 + (xo.y >> 16) + (d4 << 4));
                uint4 q0 = *p0, q1 = *p1;
                _Float16 x0h = __builtin_bit_cast(_Float16, (unsigned short)(xo.x & 0xffffu));
                _Float16 x1h = __builtin_bit_cast(_Float16, (unsigned short)(xo.y & 0xffffu));
                h2 x0 = {x0h, x0h}, x1 = {x1h, x1h};
                h2 repa = (x0 * __builtin_bit_cast(h2, q0.x) + __builtin_bit_cast(h2, q0.y))
                        * (x1 * __builtin_bit_cast(h2, q1.x) + __builtin_bit_cast(h2, q1.y));
                h2 repb = (x0 * __builtin_bit_cast(h2, q0.z) + __builtin_bit_cast(h2, q0.w))
                        * (x1 * __builtin_bit_cast(h2, q1.z) + __builtin_bit_cast(h2, q1.w));
                wtA[i] = __builtin_bit_cast(unsigned int, (h2)(repa * wv0));
                wtB[i] = __builtin_bit_cast(unsigned int, (h2)(repb * wv1));
                sWt[cell*8 + d4] = make_uint2(wtA[i], wtB[i]);
            }
        }
    }
    __syncthreads();                        // sWt ready for all waves

    if (w != 0) {
#pragma unroll
        for (int i = 0; i < CSLOT; ++i) {
            int cell = g + 8*i;
            if (cell < NCELL) {
                uint2 v = sWt[cell*8 + d4];
                wtA[i] = v.x; wtB[i] = v.y;
            }
        }
    }

    // ======== stripe items (this wave only; no per-item barriers) ========
    for (int j = 0; j < nstripe; ++j) {
        float xc[4];
#pragma unroll
        for (int r = 0; r < 4; ++r) xc[r] = xp[r];

        // prefetch next stripe item (latency hidden behind S+C)
        if (j + 1 < nstripe) {
            const float* row = ctx + (size_t)user_items[b*LLEN + w + NWAVE*(j+1)] * NSCAL;
#pragma unroll
            for (int r = 0; r < 4; ++r) {
                int idx = lane + 64*r;
                if (idx < NSCAL) xp[r] = row[idx];
            }
        }

        // ---- phase S: binary-search segment, pack {fp16(x)|rowoff} ------
#pragma unroll
        for (int r = 0; r < 4; ++r) {
            int idx = lane + 64*r;
            if (idx < NSCAL) {
                float xv = xc[r];
                int base = sc[r]*THRP;
                int pos = 0;
                pos += (sThrS[base + pos + 15] < xv) ? 16 : 0;
                pos += (sThrS[base + pos + 7]  < xv) ? 8  : 0;
                pos += (sThrS[base + pos + 3]  < xv) ? 4  : 0;
                pos += (sThrS[base + pos + 1]  < xv) ? 2  : 0;
                pos += (sThrS[base + pos]      < xv) ? 1  : 0;
                unsigned int off = (unsigned int)((sc[r]*NSEG + pos) << 7);
                _Float16 xh = (_Float16)xv;
                unsigned int word = (unsigned int)__builtin_bit_cast(unsigned short, xh)
                                  | (off << 16);
                *(unsigned int*)(sxoB + sdst[r]) = word;
            }
        }
        __builtin_amdgcn_wave_barrier();

        // ---- phase C: 100 cells x 32 d by this wave alone ----------------
#pragma unroll
        for (int i = 0; i < CSLOT; ++i) {
            int cell = g + 8*i;
            if (cell < NCELL) {
                uint2 xo = sxo[w][cell];
                const uint4* p0 = (const uint4*)((const char*)sAB16 + (xo.x >> 16) + (d4 << 4));
                const uint4* p1 = (const uint4*)((const char*)sAB16 + (xo.y >> 16) + (d4 << 4));
                uint4 q0 = *p0, q1 = *p1;
                _Float16 x0h = __builtin_bit_cast(_Float16, (unsigned short)(xo.x & 0xffffu));
                _Float16 x1h = __builtin_bit_cast(_Float16, (unsigned short)(xo.y & 0xffffu));
                h2 x0 = {x0h, x0h}, x1 = {x1h, x1h};
                h2 repa = (x0 * __builtin_bit_cast(h2, q0.x) + __builtin_bit_cast(h2, q0.y))
                        * (x1 * __builtin_bit_cast(h2, q1.x) + __builtin_bit_cast(h2, q1.y));
                h2 repb = (x0 * __builtin_bit_cast(h2, q0.z) + __builtin_bit_cast(h2, q0.w))
                        * (x1 * __builtin_bit_cast(h2, q1.z) + __builtin_bit_cast(h2, q1.w));
                acc[i] = dot2_acc(repa, __builtin_bit_cast(h2, wtA[i]),
                         dot2_acc(repb, __builtin_bit_cast(h2, wtB[i]), acc[i]));
            }
        }
        __builtin_amdgcn_wave_barrier();
    }

    // ---- epilogue: 8-lane reduce, cross-wave combine, sigmoid -----------
#pragma unroll
    for (int i = 0; i < CSLOT; ++i) {
        int cell = g + 8*i;
        float v = acc[i];
        v += __shfl_xor(v, 1, 64);
        v += __shfl_xor(v, 2, 64);
        v += __shfl_xor(v, 4, 64);
        if (d4 == 0 && cell < NCELL) pRed[w][cell] = v;
    }
    __syncthreads();
    if (tid < NCELL) {
        float p = 0.f;
#pragma unroll
        for (int q = 0; q < NWAVE; ++q) p += pRed[q][tid];
        out[b*NCELL + tid] = 1.f / (1.f + expf(-(p*inv_len + bo)));
    }
}

extern "C" void kernel_launch(void* const* d_in, const int* in_sizes, int n_in,
                              void* d_out, int out_size, void* d_ws, size_t ws_size,
                              hipStream_t stream) {
    const float* ctx   = (const float*)d_in[0];
    const float* W1    = (const float*)d_in[1];
    const float* b1    = (const float*)d_in[2];
    const float* W2    = (const float*)d_in[3];
    const float* b2    = (const float*)d_in[4];
    const float* Wout  = (const float*)d_in[5];
    const float* bout  = (const float*)d_in[6];
    const int* item_idxs  = (const int*)d_in[7];
    const int* user_items = (const int*)d_in[8];
    const int* user_lens  = (const int*)d_in[9];
    float* out = (float*)d_out;
    (void)d_ws; (void)ws_size;                 // workspace no longer used

    cnn_main<<<BATCH, 512, 0, stream>>>(ctx, W1, b1, W2, b2, Wout, bout,
                                        item_idxs, user_items, user_lens, out);
}

// Round 3
// 119.347 us; speedup vs baseline: 1.4303x; 1.4303x over previous
//
#include <hip/hip_runtime.h>
#include <math.h>

// Problem constants (fixed by the reference).
#define NITEMS 50000
#define BATCH  512
#define LLEN   50
#define KTOP   20
#define HDIM   32
#define DDIM   32
#define NCH    5
#define NSEG   33             // H+1 piecewise-linear segments
#define NSCAL  200            // scalars per item
#define NCELL  100            // (c,k) cells
#define THRP   33             // padded LDS stride for sorted thresholds
#define NWAVE  8              // waves per block
#define CSLOT  13             // ceil(100/8) cells per 8-lane group

typedef _Float16 h2 __attribute__((ext_vector_type(2)));

static __device__ __forceinline__ float dot2_acc(h2 a, h2 b, float c) {
#if __has_builtin(__builtin_amdgcn_fdot2)
    return __builtin_amdgcn_fdot2(a, b, c, false);
#else
    return fmaf((float)a.x, (float)b.x, fmaf((float)a.y, (float)b.y, c));
#endif
}

// ---------------------------------------------------------------------------
// R14: single-kernel fold (R13, proven correct: absmax 0.0) with the prologue
// AB build replaced by a prefix/suffix scan.  R13's build was the ~80us
// regression: 10.3 elements/thread x 32-deep h-loop with W2g loads under a
// data-dependent branch -> ~330 serialized conditional-load iterations.
// The scan form: 160 threads own one (c,d) each; segment s -> s+1 moves
// exactly the rank-s hidden unit across the active boundary (positive w:
// joins prefix; negative w: leaves suffix).  ~65 short iterations with
// UNCONDITIONAL loads (predicated adds) -> fully pipelinable.
// The rank->row lookup runs concurrently on wave 7 (was a serial phase).
// Summation-order deltas are few-f32-ulp pre-fp16-rounding: absorbed.
//
// Main body from `const int b = ...` onward is R13/R11 VERBATIM
// (spill-fragile; do NOT restructure the stripe loop without checking
// WRITE_SIZE for spills).
// ---------------------------------------------------------------------------
__global__ __launch_bounds__(512, 4) void cnn_main(
        const float* __restrict__ ctx,
        const float* __restrict__ W1g, const float* __restrict__ b1g,
        const float* __restrict__ W2g, const float* __restrict__ b2g,
        const float* __restrict__ Wout, const float* __restrict__ bout,
        const int* __restrict__ item_idxs, const int* __restrict__ user_items,
        const int* __restrict__ user_lens,
        float* __restrict__ out) {
    __shared__ unsigned int sAB16[NCH*NSEG*32];  // 21120 B, swizzled fp16
    __shared__ float  sThrS[NCH*THRP];           // sorted thr, stride 33
    __shared__ uint2  sxo[NWAVE][NCELL];         // {x0h|off0<<16, x1h|off1<<16}
    __shared__ uint2  sWt[NCELL*8];              // [cell*8+d4] target wt bits
    __shared__ float  pRed[NWAVE][NCELL];        // per-wave scalar partials

    const int tid  = threadIdx.x;
    const int w    = tid >> 6;              // wave 0..7
    const int lane = tid & 63;
    const int g    = lane >> 3;             // cell sub-group 0..7
    const int d4   = lane & 7;              // covers d = 4*d4 .. 4*d4+3

    // Sorted pairing (ranks r and 511-r co-resident under round-robin).
    const int rank = (blockIdx.x < 256) ? blockIdx.x : (767 - blockIdx.x);

    // ---- prologue temporaries overlaid on later-phase LDS ----------------
    // pRed (3200 B) is first written in the epilogue; sWt first written in
    // the target phase (by wave 0, after wave 7 is done reading sHist).
    float* sW1f  = &pRed[0][0];                  // 160 f
    float* sB1f  = sW1f + NCH*HDIM;              // 160 f
    float* sThrT = sB1f + NCH*HDIM;              // 160 f
    int*   sInv  = (int*)(sThrT + NCH*HDIM);     // 160 i (rank -> h)
    int*   sBp   = sInv + NCH*HDIM;              // 1 i  (2564 B total <= 3200)
    int*   sHist = (int*)&sWt[0];                // 51 i

    // ---- B0..B1: stage W1/b1, zero histogram, init sBp fallback ----------
    for (int i = tid; i < NCH*HDIM; i += 512) { sW1f[i] = W1g[i]; sB1f[i] = b1g[i]; }
    if (tid <= LLEN) sHist[tid] = 0;
    if (tid == 0) *sBp = rank;                   // in-bounds fallback
    __syncthreads();

    // ---- B1..B2: thresholds; length histogram ----------------------------
    for (int i = tid; i < NCH*HDIM; i += 512) {
        float wv = sW1f[i];
        sThrT[i] = (wv != 0.f) ? (-sB1f[i] / wv) : INFINITY;
    }
    atomicAdd(&sHist[user_lens[tid]], 1);        // counts are order-invariant
    __syncthreads();

    // ---- B2..B3: rank pass -> sorted thresholds + INVERSE map; prefix ----
    for (int i = tid; i < NCH*HDIM; i += 512) {
        int c = i >> 5, h = i & 31;
        float thr = sThrT[i];
        int rnk = 0;
        for (int hh = 0; hh < HDIM; ++hh) {
            float t2 = sThrT[(c<<5) + hh];
            rnk += (t2 < thr || (t2 == thr && hh < h)) ? 1 : 0;
        }
        sInv[(c<<5) + rnk] = h;                  // bijective per channel
        sThrS[c*THRP + rnk] = thr;
    }
    if (tid == 0) {
        int accum = 0;
        for (int l = 1; l <= LLEN; ++l) { int cc = sHist[l]; sHist[l] = accum; accum += cc; }
    }
    __syncthreads();

    // ---- B3..B4: AB table via prefix/suffix scan  ||  wave-7 rank scan ---
    if (tid < NCH*DDIM) {
        const int c = tid >> 5, d = tid & 31;
        // Running sums: pa/pb = positive-w prefix (ranks < s);
        // sa/sb = negative-w suffix (ranks >= s); zb = w==0 && b>0 class.
        float pa = 0.f, pb = 0.f, sa = 0.f, sb = 0.f, zb = 0.f;
#pragma unroll
        for (int h = 0; h < HDIM; ++h) {
            float wv = sW1f[(c<<5) + h];
            float bb = sB1f[(c<<5) + h];
            float w2 = W2g[(((c<<5) + h) << 5) + d];
            float aw = wv * w2, bw = bb * w2;
            if (wv < 0.f) { sa += aw; sb += bw; }
            else if (wv == 0.f && bb > 0.f) { zb += bw; }
        }
        const float b2v = b2g[(c<<5) + d] + zb;
        unsigned short* ab = (unsigned short*)sAB16;
        const int dq = d >> 2, dd = d & 3;
        const int sub = 4*(dd>>1) + (dd&1);
#pragma unroll
        for (int s = 0; s < NSEG; ++s) {
            _Float16 ah = (_Float16)(pa + sa);
            _Float16 bh = (_Float16)(pb + sb + b2v);
            int base = ((c*NSEG + s)*32 + dq*4)*2;          // ushort index
            ab[base + sub]     = __builtin_bit_cast(unsigned short, ah);
            ab[base + sub + 2] = __builtin_bit_cast(unsigned short, bh);
            if (s < HDIM) {
                int hh = sInv[(c<<5) + s];                  // rank-s unit
                float wv = sW1f[(c<<5) + hh];
                float bb = sB1f[(c<<5) + hh];
                float w2 = W2g[(((c<<5) + hh) << 5) + d];
                float aw = wv * w2, bw = bb * w2;
                if (wv > 0.f)      { pa += aw; pb += bw; }   // joins prefix
                else if (wv < 0.f) { sa -= aw; sb -= bw; }   // leaves suffix
            }
        }
    } else if (w == 7) {
        // Rank->row lookup (stable counting-sort; deterministic across
        // blocks).  Whole wave 7 executes this branch together.
        int l = lane;
        bool inb = (l >= 1 && l <= LLEN) && (sHist[l] <= rank)
                && (l == LLEN || sHist[l+1] > rank);
        unsigned long long mm = __ballot(inb);
        if (mm != 0ull) {
            int lstar = (int)__builtin_ctzll(mm);
            int need = rank - sHist[lstar];
            if (need < 0) need = 0;
            for (int chunk = 0; chunk < BATCH/64; ++chunk) {
                int j = (chunk << 6) + lane;
                unsigned long long mb = __ballot(user_lens[j] == lstar);
                int cnt = __popcll(mb);
                if (need < cnt) {
                    if (((mb >> lane) & 1ull) &&
                        __popcll(mb & ((1ull << lane) - 1ull)) == need)
                        *sBp = j;
                    break;
                }
                need -= cnt;
            }
        }
    }
    __syncthreads();                        // prologue results visible to all

    // ======================================================================
    // From here on: R13 main body, verbatim (b sourced from sBp).
    // ======================================================================
    const int b    = (*sBp) & (BATCH - 1);  // mask: never out of bounds
    const int len  = user_lens[b];          // >= 1
    const float inv_len = 1.f / (float)len;
    const float bo = bout[0];
    const h2 wv0 = {(_Float16)Wout[4*d4],     (_Float16)Wout[4*d4 + 1]};
    const h2 wv1 = {(_Float16)Wout[4*d4 + 2], (_Float16)Wout[4*d4 + 3]};

    // Per-(lane,round) phase-S constants (fixed across items).
    int sc[4], sdst[4];
#pragma unroll
    for (int r = 0; r < 4; ++r) {
        int idx  = lane + 64*r;
        int c    = idx / 40, rr = idx - c*40;
        int cell = c*KTOP + (rr % KTOP);
        sc[r]   = c;
        sdst[r] = cell*8 + (rr / KTOP)*4;   // byte offset in sxo[w]
    }

    const int nstripe = (len > w) ? ((len - w + NWAVE - 1) / NWAVE) : 0;

    unsigned int wtA[CSLOT], wtB[CSLOT];    // target rep * Wout (h2 bits)
    float acc[CSLOT];
#pragma unroll
    for (int i = 0; i < CSLOT; ++i) acc[i] = 0.f;

    char* sxoB = (char*)&sxo[w][0];

    // Prefetch this wave's first stripe item (overlaps wave 0's target).
    float xp[4] = {0.f, 0.f, 0.f, 0.f};
    if (nstripe > 0) {
        const float* row = ctx + (size_t)user_items[b*LLEN + w] * NSCAL;
#pragma unroll
        for (int r = 0; r < 4; ++r) {
            int idx = lane + 64*r;
            if (idx < NSCAL) xp[r] = row[idx];
        }
    }

    // ======== target item: wave 0 only, broadcast via sWt ================
    if (w == 0) {
        float xt[4] = {0.f, 0.f, 0.f, 0.f};
        const float* row = ctx + (size_t)item_idxs[b] * NSCAL;
#pragma unroll
        for (int r = 0; r < 4; ++r) {
            int idx = lane + 64*r;
            if (idx < NSCAL) xt[r] = row[idx];
        }
#pragma unroll
        for (int r = 0; r < 4; ++r) {
            int idx = lane + 64*r;
            if (idx < NSCAL) {
                float xv = xt[r];
                int base = sc[r]*THRP;
                int pos = 0;
                pos += (sThrS[base + pos + 15] < xv) ? 16 : 0;
                pos += (sThrS[base + pos + 7]  < xv) ? 8  : 0;
                pos += (sThrS[base + pos + 3]  < xv) ? 4  : 0;
                pos += (sThrS[base + pos + 1]  < xv) ? 2  : 0;
                pos += (sThrS[base + pos]      < xv) ? 1  : 0;
                unsigned int off = (unsigned int)((sc[r]*NSEG + pos) << 7);
                _Float16 xh = (_Float16)xv;
                unsigned int word = (unsigned int)__builtin_bit_cast(unsigned short, xh)
                                  | (off << 16);
                *(unsigned int*)(sxoB + sdst[r]) = word;
            }
        }
        __builtin_amdgcn_wave_barrier();
#pragma unroll
        for (int i = 0; i < CSLOT; ++i) {
            int cell = g + 8*i;
            if (cell < NCELL) {
                uint2 xo = sxo[0][cell];
                const uint4* p0 = (const uint4*)((const char*)sAB16 + (xo.x >> 16) + (d4 << 4));
                const uint4* p1 = (const uint4*)((const char*)sAB16 + (xo.y >> 16) + (d4 << 4));
                uint4 q0 = *p0, q1 = *p1;
                _Float16 x0h = __builtin_bit_cast(_Float16, (unsigned short)(xo.x & 0xffffu));
                _Float16 x1h = __builtin_bit_cast(_Float16, (unsigned short)(xo.y & 0xffffu));
                h2 x0 = {x0h, x0h}, x1 = {x1h, x1h};
                h2 repa = (x0 * __builtin_bit_cast(h2, q0.x) + __builtin_bit_cast(h2, q0.y))
                        * (x1 * __builtin_bit_cast(h2, q1.x) + __builtin_bit_cast(h2, q1.y));
                h2 repb = (x0 * __builtin_bit_cast(h2, q0.z) + __builtin_bit_cast(h2, q0.w))
                        * (x1 * __builtin_bit_cast(h2, q1.z) + __builtin_bit_cast(h2, q1.w));
                wtA[i] = __builtin_bit_cast(unsigned int, (h2)(repa * wv0));
                wtB[i] = __builtin_bit_cast(unsigned int, (h2)(repb * wv1));
                sWt[cell*8 + d4] = make_uint2(wtA[i], wtB[i]);
            }
        }
    }
    __syncthreads();                        // sWt ready for all waves

    if (w != 0) {
#pragma unroll
        for (int i = 0; i < CSLOT; ++i) {
            int cell = g + 8*i;
            if (cell < NCELL) {
                uint2 v = sWt[cell*8 + d4];
                wtA[i] = v.x; wtB[i] = v.y;
            }
        }
    }

    // ======== stripe items (this wave only; no per-item barriers) ========
    for (int j = 0; j < nstripe; ++j) {
        float xc[4];
#pragma unroll
        for (int r = 0; r < 4; ++r) xc[r] = xp[r];

        // prefetch next stripe item (latency hidden behind S+C)
        if (j + 1 < nstripe) {
            const float* row = ctx + (size_t)user_items[b*LLEN + w + NWAVE*(j+1)] * NSCAL;
#pragma unroll
            for (int r = 0; r < 4; ++r) {
                int idx = lane + 64*r;
                if (idx < NSCAL) xp[r] = row[idx];
            }
        }

        // ---- phase S: binary-search segment, pack {fp16(x)|rowoff} ------
#pragma unroll
        for (int r = 0; r < 4; ++r) {
            int idx = lane + 64*r;
            if (idx < NSCAL) {
                float xv = xc[r];
                int base = sc[r]*THRP;
                int pos = 0;
                pos += (sThrS[base + pos + 15] < xv) ? 16 : 0;
                pos += (sThrS[base + pos + 7]  < xv) ? 8  : 0;
                pos += (sThrS[base + pos + 3]  < xv) ? 4  : 0;
                pos += (sThrS[base + pos + 1]  < xv) ? 2  : 0;
                pos += (sThrS[base + pos]      < xv) ? 1  : 0;
                unsigned int off = (unsigned int)((sc[r]*NSEG + pos) << 7);
                _Float16 xh = (_Float16)xv;
                unsigned int word = (unsigned int)__builtin_bit_cast(unsigned short, xh)
                                  | (off << 16);
                *(unsigned int*)(sxoB + sdst[r]) = word;
            }
        }
        __builtin_amdgcn_wave_barrier();

        // ---- phase C: 100 cells x 32 d by this wave alone ----------------
#pragma unroll
        for (int i = 0; i < CSLOT; ++i) {
            int cell = g + 8*i;
            if (cell < NCELL) {
                uint2 xo = sxo[w][cell];
                const uint4* p0 = (const uint4*)((const char*)sAB16 + (xo.x >> 16) + (d4 << 4));
                const uint4* p1 = (const uint4*)((const char*)sAB16 + (xo.y >> 16) + (d4 << 4));
                uint4 q0 = *p0, q1 = *p1;
                _Float16 x0h = __builtin_bit_cast(_Float16, (unsigned short)(xo.x & 0xffffu));
                _Float16 x1h = __builtin_bit_cast(_Float16, (unsigned short)(xo.y & 0xffffu));
                h2 x0 = {x0h, x0h}, x1 = {x1h, x1h};
                h2 repa = (x0 * __builtin_bit_cast(h2, q0.x) + __builtin_bit_cast(h2, q0.y))
                        * (x1 * __builtin_bit_cast(h2, q1.x) + __builtin_bit_cast(h2, q1.y));
                h2 repb = (x0 * __builtin_bit_cast(h2, q0.z) + __builtin_bit_cast(h2, q0.w))
                        * (x1 * __builtin_bit_cast(h2, q1.z) + __builtin_bit_cast(h2, q1.w));
                acc[i] = dot2_acc(repa, __builtin_bit_cast(h2, wtA[i]),
                         dot2_acc(repb, __builtin_bit_cast(h2, wtB[i]), acc[i]));
            }
        }
        __builtin_amdgcn_wave_barrier();
    }

    // ---- epilogue: 8-lane reduce, cross-wave combine, sigmoid -----------
#pragma unroll
    for (int i = 0; i < CSLOT; ++i) {
        int cell = g + 8*i;
        float v = acc[i];
        v += __shfl_xor(v, 1, 64);
        v += __shfl_xor(v, 2, 64);
        v += __shfl_xor(v, 4, 64);
        if (d4 == 0 && cell < NCELL) pRed[w][cell] = v;
    }
    __syncthreads();
    if (tid < NCELL) {
        float p = 0.f;
#pragma unroll
        for (int q = 0; q < NWAVE; ++q) p += pRed[q][tid];
        out[b*NCELL + tid] = 1.f / (1.f + expf(-(p*inv_len + bo)));
    }
}

extern "C" void kernel_launch(void* const* d_in, const int* in_sizes, int n_in,
                              void* d_out, int out_size, void* d_ws, size_t ws_size,
                              hipStream_t stream) {
    const float* ctx   = (const float*)d_in[0];
    const float* W1    = (const float*)d_in[1];
    const float* b1    = (const float*)d_in[2];
    const float* W2    = (const float*)d_in[3];
    const float* b2    = (const float*)d_in[4];
    const float* Wout  = (const float*)d_in[5];
    const float* bout  = (const float*)d_in[6];
    const int* item_idxs  = (const int*)d_in[7];
    const int* user_items = (const int*)d_in[8];
    const int* user_lens  = (const int*)d_in[9];
    float* out = (float*)d_out;
    (void)d_ws; (void)ws_size;                 // workspace no longer used

    cnn_main<<<BATCH, 512, 0, stream>>>(ctx, W1, b1, W2, b2, Wout, bout,
                                        item_idxs, user_items, user_lens, out);
}